// Round 1
// baseline (441.752 us; speedup 1.0000x reference)
//
#include <hip/hip_runtime.h>
#include <hip/hip_bf16.h>
#include <cstdint>

// Problem constants
#define BB 16
#define LL 1024
#define DD 128
#define NH 8
#define HDIM 16
#define NROWS (BB*LL)          // 16384
#define ARR 2097152            // NROWS*DD floats per array

// ws layout (floats): [0..63] header (flag int at word 0)
// Q at +64, K at +64+ARR, V at +64+2*ARR.
// ctx overwrites Q; x1 overwrites K; h1 overwrites V.

__device__ __forceinline__ float waveReduceSum(float v) {
    #pragma unroll
    for (int i = 1; i < 64; i <<= 1) v += __shfl_xor(v, i, 64);
    return v;
}

// ---------------------------------------------------------------- detect mask
__global__ void k_detect(const uint32_t* __restrict__ m, int* __restrict__ flag) {
    if (threadIdx.x == 0) {
        int f = 0;
        for (int i = 0; i < 256; ++i) f |= (m[i] > 1u) ? 1 : 0;
        *flag = f;   // 1 => byte-encoded mask, 0 => int32-encoded mask
    }
}

// ---------------------------------------------------------------- generic GEMM
// out[row][col] = act( X[row][:] @ W[:,gcol] + bias[gcol] ), rows=16384, K=128.
// Tile: 64 rows x 64 cols, K split in 2. If split!=0, output cols map to the
// 3 chunked QKV arrays (each [16384][128]).
__global__ __launch_bounds__(256) void k_gemm(const float* __restrict__ X,
        const float* __restrict__ W, const float* __restrict__ bias,
        float* __restrict__ out, int wstride, int split, int relu)
{
    __shared__ float Xt[64][68];
    __shared__ float Wt[64][64];
    const int r0  = blockIdx.x * 64;
    const int gc0 = blockIdx.y * 64;
    const int t   = threadIdx.x;
    const int rg  = t >> 4;       // 0..15 -> rows rg*4..+3
    const int cg  = t & 15;       // cols cg*4..+3

    float acc[4][4];
    {
        float4 bv = *(const float4*)(bias + gc0 + cg * 4);
        #pragma unroll
        for (int i = 0; i < 4; ++i) {
            acc[i][0] = bv.x; acc[i][1] = bv.y; acc[i][2] = bv.z; acc[i][3] = bv.w;
        }
    }
    for (int kt = 0; kt < 2; ++kt) {
        __syncthreads();
        #pragma unroll
        for (int i = 0; i < 4; ++i) {           // stage X: 64 rows x 64 k
            int e = t + 256 * i;                // float4 units
            int r = e >> 4, c4 = e & 15;
            *(float4*)&Xt[r][c4 * 4] =
                *(const float4*)(X + (size_t)(r0 + r) * 128 + kt * 64 + c4 * 4);
        }
        #pragma unroll
        for (int i = 0; i < 4; ++i) {           // stage W: 64 k x 64 cols
            int e = t + 256 * i;
            int k = e >> 4, c4 = e & 15;
            *(float4*)&Wt[k][c4 * 4] =
                *(const float4*)(W + (size_t)(kt * 64 + k) * wstride + gc0 + c4 * 4);
        }
        __syncthreads();
        #pragma unroll 8
        for (int k = 0; k < 64; ++k) {
            float xv[4];
            #pragma unroll
            for (int i = 0; i < 4; ++i) xv[i] = Xt[rg * 4 + i][k];
            float4 wv = *(const float4*)&Wt[k][cg * 4];
            #pragma unroll
            for (int i = 0; i < 4; ++i) {
                acc[i][0] += xv[i] * wv.x;
                acc[i][1] += xv[i] * wv.y;
                acc[i][2] += xv[i] * wv.z;
                acc[i][3] += xv[i] * wv.w;
            }
        }
    }
    float* o;
    if (split) o = out + (size_t)(gc0 >> 7) * ARR + (size_t)r0 * 128 + (gc0 & 127);
    else       o = out + (size_t)r0 * 128 + gc0;
    #pragma unroll
    for (int i = 0; i < 4; ++i) {
        float4 v = { acc[i][0], acc[i][1], acc[i][2], acc[i][3] };
        if (relu) {
            v.x = fmaxf(v.x, 0.f); v.y = fmaxf(v.y, 0.f);
            v.z = fmaxf(v.z, 0.f); v.w = fmaxf(v.w, 0.f);
        }
        *(float4*)(o + (size_t)(rg * 4 + i) * 128 + cg * 4) = v;
    }
}

// ---------------------------------------------------------------- attention
// One block: (batch b, 32 q-rows) x all 8 heads. Thread = one (h, q) row.
// Online softmax over k, K/V tiles of 32 staged in LDS, mask read once for all
// heads and converted to additive f32 bias in LDS.
__global__ __launch_bounds__(256, 2) void k_attn(float* __restrict__ ws,
        const void* __restrict__ maskp, const int* __restrict__ flag)
{
    __shared__ float Kt[32][128];
    __shared__ float Vt[32][128];
    __shared__ float Bt[32][33];
    const int b  = blockIdx.y;
    const int q0 = blockIdx.x * 32;
    const int t  = threadIdx.x;
    const int h  = t >> 5;        // 0..7
    const int q  = t & 31;        // 0..31
    const float* Q = ws;
    const float* K = ws + ARR;
    const float* V = ws + 2 * ARR;
    const size_t row = (size_t)b * 1024 + q0 + q;

    float4 qr[4];
    {
        const float4* qp = (const float4*)(Q + row * 128 + h * 16);
        qr[0] = qp[0]; qr[1] = qp[1]; qr[2] = qp[2]; qr[3] = qp[3];
    }
    float m = -INFINITY, l = 0.f;
    float4 acc[4];
    #pragma unroll
    for (int j = 0; j < 4; ++j) acc[j] = float4{0.f, 0.f, 0.f, 0.f};

    const int bytemask = *flag;
    const uint8_t* m8  = (const uint8_t*)maskp;
    const int*     m32 = (const int*)maskp;

    for (int kt = 0; kt < 32; ++kt) {
        const int k0 = kt * 32;
        __syncthreads();
        {   // stage K,V tiles (32x128 each), linear float4 copy
            const float4* Ksrc = (const float4*)(K + ((size_t)b * 1024 + k0) * 128);
            const float4* Vsrc = (const float4*)(V + ((size_t)b * 1024 + k0) * 128);
            float4* Kd = (float4*)&Kt[0][0];
            float4* Vd = (float4*)&Vt[0][0];
            #pragma unroll
            for (int i = 0; i < 4; ++i) {
                Kd[t + 256 * i] = Ksrc[t + 256 * i];
                Vd[t + 256 * i] = Vsrc[t + 256 * i];
            }
        }
        {   // stage mask bias tile 32q x 32k
            int mq = t >> 3, ko = (t & 7) * 4;
            size_t mb = ((size_t)b << 20) + (size_t)(q0 + mq) * 1024 + k0 + ko;
            if (bytemask) {
                uint32_t v = *(const uint32_t*)(m8 + mb);
                Bt[mq][ko + 0] = (v & 0x000000ffu) ? -1e30f : 0.f;
                Bt[mq][ko + 1] = (v & 0x0000ff00u) ? -1e30f : 0.f;
                Bt[mq][ko + 2] = (v & 0x00ff0000u) ? -1e30f : 0.f;
                Bt[mq][ko + 3] = (v & 0xff000000u) ? -1e30f : 0.f;
            } else {
                int4 v = *(const int4*)(m32 + mb);
                Bt[mq][ko + 0] = v.x ? -1e30f : 0.f;
                Bt[mq][ko + 1] = v.y ? -1e30f : 0.f;
                Bt[mq][ko + 2] = v.z ? -1e30f : 0.f;
                Bt[mq][ko + 3] = v.w ? -1e30f : 0.f;
            }
        }
        __syncthreads();
        #pragma unroll 4
        for (int kk = 0; kk < 32; ++kk) {
            const float4* kp = (const float4*)&Kt[kk][h * 16];
            float s = 0.f;
            #pragma unroll
            for (int j = 0; j < 4; ++j) {
                float4 kf = kp[j];
                s += qr[j].x * kf.x + qr[j].y * kf.y + qr[j].z * kf.z + qr[j].w * kf.w;
            }
            s = s * 0.25f + Bt[q][kk];
            if (s > m) {                       // rare after warmup
                float sc = __expf(m - s);
                m = s; l *= sc;
                #pragma unroll
                for (int j = 0; j < 4; ++j) {
                    acc[j].x *= sc; acc[j].y *= sc; acc[j].z *= sc; acc[j].w *= sc;
                }
            }
            float p = __expf(s - m);
            l += p;
            const float4* vp = (const float4*)&Vt[kk][h * 16];
            #pragma unroll
            for (int j = 0; j < 4; ++j) {
                float4 vf = vp[j];
                acc[j].x += p * vf.x; acc[j].y += p * vf.y;
                acc[j].z += p * vf.z; acc[j].w += p * vf.w;
            }
        }
    }
    float inv = 1.f / l;
    float* o = ws + row * 128 + h * 16;        // ctx overwrites Q (own rows only)
    #pragma unroll
    for (int j = 0; j < 4; ++j) {
        float4 v = { acc[j].x * inv, acc[j].y * inv, acc[j].z * inv, acc[j].w * inv };
        ((float4*)o)[j] = v;
    }
}

// ---------------------------------------------------------------- LN1
// x1 = LN(x + ctx) ; one row per wave
__global__ __launch_bounds__(256) void k_ln1(const float* __restrict__ x,
        const float* __restrict__ ctx, const float* __restrict__ g1,
        const float* __restrict__ be1, float* __restrict__ x1out)
{
    const int wv = threadIdx.x >> 6, lane = threadIdx.x & 63;
    const size_t r = (size_t)blockIdx.x * 4 + wv;
    const int c = lane * 2;
    float2 xa = *(const float2*)(x   + r * 128 + c);
    float2 ca = *(const float2*)(ctx + r * 128 + c);
    float y0 = xa.x + ca.x, y1 = xa.y + ca.y;
    float mu = waveReduceSum(y0 + y1) * (1.f / 128.f);
    float d0 = y0 - mu, d1 = y1 - mu;
    float var = waveReduceSum(d0 * d0 + d1 * d1) * (1.f / 128.f);
    float rs = rsqrtf(var + 1e-5f);
    float2 g  = *(const float2*)(g1 + c);
    float2 be = *(const float2*)(be1 + c);
    float2 o = { d0 * rs * g.x + be.x, d1 * rs * g.y + be.y };
    *(float2*)(x1out + r * 128 + c) = o;
}

// ---------------------------------------------------------------- GEMM2 + LN2
// out = LN2( x1 + h1 @ W2 + b2 ). Block owns 64 full rows (all 128 cols).
__global__ __launch_bounds__(256, 2) void k_gemm2(const float* __restrict__ h1,
        const float* __restrict__ w2, const float* __restrict__ b2,
        const float* __restrict__ x1, const float* __restrict__ g2,
        const float* __restrict__ be2, float* __restrict__ out)
{
    __shared__ float Ht[64][68];
    __shared__ float Wt[64][128];
    __shared__ float red[64][17];
    __shared__ float meanv[64];
    __shared__ float rsv[64];
    const int r0 = blockIdx.x * 64;
    const int t  = threadIdx.x;
    const int rg = t >> 4;        // rows rg*4..+3
    const int cg = t & 15;        // cols cg*8..+7

    float acc[4][8];
    {
        float4 ba = *(const float4*)(b2 + cg * 8);
        float4 bb = *(const float4*)(b2 + cg * 8 + 4);
        #pragma unroll
        for (int i = 0; i < 4; ++i) {
            acc[i][0]=ba.x; acc[i][1]=ba.y; acc[i][2]=ba.z; acc[i][3]=ba.w;
            acc[i][4]=bb.x; acc[i][5]=bb.y; acc[i][6]=bb.z; acc[i][7]=bb.w;
        }
    }
    for (int kt = 0; kt < 2; ++kt) {
        __syncthreads();
        #pragma unroll
        for (int i = 0; i < 4; ++i) {           // stage h1 tile 64x64
            int e = t + 256 * i;
            int r = e >> 4, c4 = e & 15;
            *(float4*)&Ht[r][c4 * 4] =
                *(const float4*)(h1 + (size_t)(r0 + r) * 128 + kt * 64 + c4 * 4);
        }
        #pragma unroll
        for (int i = 0; i < 8; ++i) {           // stage W2 tile 64x128
            int e = t + 256 * i;
            int k = e >> 5, c4 = e & 31;
            *(float4*)&Wt[k][c4 * 4] =
                *(const float4*)(w2 + (size_t)(kt * 64 + k) * 128 + c4 * 4);
        }
        __syncthreads();
        #pragma unroll 4
        for (int k = 0; k < 64; ++k) {
            float hv[4];
            #pragma unroll
            for (int i = 0; i < 4; ++i) hv[i] = Ht[rg * 4 + i][k];
            float4 w0 = *(const float4*)&Wt[k][cg * 8];
            float4 w1 = *(const float4*)&Wt[k][cg * 8 + 4];
            #pragma unroll
            for (int i = 0; i < 4; ++i) {
                acc[i][0] += hv[i] * w0.x; acc[i][1] += hv[i] * w0.y;
                acc[i][2] += hv[i] * w0.z; acc[i][3] += hv[i] * w0.w;
                acc[i][4] += hv[i] * w1.x; acc[i][5] += hv[i] * w1.y;
                acc[i][6] += hv[i] * w1.z; acc[i][7] += hv[i] * w1.w;
            }
        }
    }
    // residual add
    float y[4][8];
    #pragma unroll
    for (int i = 0; i < 4; ++i) {
        float4 xa = *(const float4*)(x1 + (size_t)(r0 + rg * 4 + i) * 128 + cg * 8);
        float4 xb = *(const float4*)(x1 + (size_t)(r0 + rg * 4 + i) * 128 + cg * 8 + 4);
        y[i][0]=xa.x+acc[i][0]; y[i][1]=xa.y+acc[i][1]; y[i][2]=xa.z+acc[i][2]; y[i][3]=xa.w+acc[i][3];
        y[i][4]=xb.x+acc[i][4]; y[i][5]=xb.y+acc[i][5]; y[i][6]=xb.z+acc[i][6]; y[i][7]=xb.w+acc[i][7];
    }
    __syncthreads();   // red[] reuse safety (first use this pass after staging loop)
    #pragma unroll
    for (int i = 0; i < 4; ++i) {
        float s = 0.f;
        #pragma unroll
        for (int j = 0; j < 8; ++j) s += y[i][j];
        red[rg * 4 + i][cg] = s;
    }
    __syncthreads();
    if (t < 64) {
        float s = 0.f;
        #pragma unroll
        for (int j = 0; j < 16; ++j) s += red[t][j];
        meanv[t] = s * (1.f / 128.f);
    }
    __syncthreads();
    #pragma unroll
    for (int i = 0; i < 4; ++i) {
        float mu = meanv[rg * 4 + i];
        float s = 0.f;
        #pragma unroll
        for (int j = 0; j < 8; ++j) { float d = y[i][j] - mu; s += d * d; }
        red[rg * 4 + i][cg] = s;
    }
    __syncthreads();
    if (t < 64) {
        float s = 0.f;
        #pragma unroll
        for (int j = 0; j < 16; ++j) s += red[t][j];
        rsv[t] = rsqrtf(s * (1.f / 128.f) + 1e-5f);
    }
    __syncthreads();
    float4 ga = *(const float4*)(g2 + cg * 8);
    float4 gb = *(const float4*)(g2 + cg * 8 + 4);
    float4 ba = *(const float4*)(be2 + cg * 8);
    float4 bb = *(const float4*)(be2 + cg * 8 + 4);
    #pragma unroll
    for (int i = 0; i < 4; ++i) {
        int r = r0 + rg * 4 + i;
        float mu = meanv[rg * 4 + i], rs = rsv[rg * 4 + i];
        float4 o0 = { (y[i][0]-mu)*rs*ga.x + ba.x, (y[i][1]-mu)*rs*ga.y + ba.y,
                      (y[i][2]-mu)*rs*ga.z + ba.z, (y[i][3]-mu)*rs*ga.w + ba.w };
        float4 o1 = { (y[i][4]-mu)*rs*gb.x + bb.x, (y[i][5]-mu)*rs*gb.y + bb.y,
                      (y[i][6]-mu)*rs*gb.z + bb.z, (y[i][7]-mu)*rs*gb.w + bb.w };
        *(float4*)(out + (size_t)r * 128 + cg * 8)     = o0;
        *(float4*)(out + (size_t)r * 128 + cg * 8 + 4) = o1;
    }
}

// ---------------------------------------------------------------- launch
extern "C" void kernel_launch(void* const* d_in, const int* in_sizes, int n_in,
                              void* d_out, int out_size, void* d_ws, size_t ws_size,
                              hipStream_t stream)
{
    const float* x    = (const float*)d_in[0];
    const void*  mask = d_in[1];
    const float* wqkv = (const float*)d_in[2];
    const float* bqkv = (const float*)d_in[3];
    const float* w1   = (const float*)d_in[4];
    const float* b1   = (const float*)d_in[5];
    const float* w2   = (const float*)d_in[6];
    const float* b2   = (const float*)d_in[7];
    const float* g1   = (const float*)d_in[8];
    const float* be1  = (const float*)d_in[9];
    const float* g2   = (const float*)d_in[10];
    const float* be2  = (const float*)d_in[11];
    float* out = (float*)d_out;

    int*   flag = (int*)d_ws;
    float* qkv  = (float*)d_ws + 64;      // Q base
    float* ctx  = qkv;                    // ctx overwrites Q
    float* x1   = qkv + ARR;              // x1 overwrites K
    float* h1   = qkv + 2 * ARR;          // h1 overwrites V

    k_detect<<<1, 64, 0, stream>>>((const uint32_t*)mask, flag);
    k_gemm<<<dim3(256, 6), 256, 0, stream>>>(x, wqkv, bqkv, qkv, 384, 1, 0);
    k_attn<<<dim3(32, 16), 256, 0, stream>>>(qkv, mask, flag);
    k_ln1<<<4096, 256, 0, stream>>>(x, ctx, g1, be1, x1);
    k_gemm<<<dim3(256, 2), 256, 0, stream>>>(x1, w1, b1, h1, 128, 0, 1);
    k_gemm2<<<256, 256, 0, stream>>>(h1, w2, b2, x1, g2, be2, out);
}

// Round 5
// 244.160 us; speedup vs baseline: 1.8093x; 1.8093x over previous
//
#include <hip/hip_runtime.h>
#include <cstdint>

#define NROWS 16384

typedef short short8 __attribute__((ext_vector_type(8)));
typedef float f32x4  __attribute__((ext_vector_type(4)));
typedef float f32x16 __attribute__((ext_vector_type(16)));

static __device__ __forceinline__ unsigned short f2bf(float f) {
    union { float f; uint32_t u; } v; v.f = f;
    uint32_t r = v.u + 0x7fffu + ((v.u >> 16) & 1u);   // RNE
    return (unsigned short)(r >> 16);
}

// ---------------------------------------------------------------- detect mask encoding
__global__ void k_detect(const uint32_t* __restrict__ m, int* __restrict__ flag) {
    if (threadIdx.x == 0) {
        int f = 0;
        for (int i = 0; i < 256; ++i) f |= (m[i] > 1u) ? 1 : 0;
        *flag = f;   // 1 => byte-encoded bool mask, 0 => int32 mask
    }
}

// ---------------------------------------------------------------- generic GEMM (fp32 compute)
// out[row][col] = act( X[row][:] @ W[:,gcol] + bias[gcol] ), rows=16384, K=128.
// outbf!=0: QKV mode -> writes bf16 into 3 chunked arrays (each [16384][128]),
// Q (array 0) pre-scaled by 0.25 (= hd^-0.5).
__global__ __launch_bounds__(256) void k_gemm(const float* __restrict__ X,
        const float* __restrict__ W, const float* __restrict__ bias,
        void* __restrict__ outp, int wstride, int relu, int outbf)
{
    __shared__ float Xt[64][68];
    __shared__ float Wt[64][64];
    const int r0  = blockIdx.x * 64;
    const int gc0 = blockIdx.y * 64;
    const int t   = threadIdx.x;
    const int rg  = t >> 4;       // rows rg*4..+3
    const int cg  = t & 15;       // cols cg*4..+3

    float acc[4][4];
    {
        float4 bv = *(const float4*)(bias + gc0 + cg * 4);
        #pragma unroll
        for (int i = 0; i < 4; ++i) {
            acc[i][0] = bv.x; acc[i][1] = bv.y; acc[i][2] = bv.z; acc[i][3] = bv.w;
        }
    }
    for (int kt = 0; kt < 2; ++kt) {
        __syncthreads();
        #pragma unroll
        for (int i = 0; i < 4; ++i) {           // stage X: 64 rows x 64 k
            int e = t + 256 * i;
            int r = e >> 4, c4 = e & 15;
            *(float4*)&Xt[r][c4 * 4] =
                *(const float4*)(X + (size_t)(r0 + r) * 128 + kt * 64 + c4 * 4);
        }
        #pragma unroll
        for (int i = 0; i < 4; ++i) {           // stage W: 64 k x 64 cols
            int e = t + 256 * i;
            int k = e >> 4, c4 = e & 15;
            *(float4*)&Wt[k][c4 * 4] =
                *(const float4*)(W + (size_t)(kt * 64 + k) * wstride + gc0 + c4 * 4);
        }
        __syncthreads();
        #pragma unroll 8
        for (int k = 0; k < 64; ++k) {
            float xv[4];
            #pragma unroll
            for (int i = 0; i < 4; ++i) xv[i] = Xt[rg * 4 + i][k];
            float4 wv = *(const float4*)&Wt[k][cg * 4];
            #pragma unroll
            for (int i = 0; i < 4; ++i) {
                acc[i][0] += xv[i] * wv.x;
                acc[i][1] += xv[i] * wv.y;
                acc[i][2] += xv[i] * wv.z;
                acc[i][3] += xv[i] * wv.w;
            }
        }
    }
    if (outbf) {
        unsigned short* o16 = (unsigned short*)outp;
        const int a = gc0 >> 7;                  // 0=Q,1=K,2=V
        const float scale = (a == 0) ? 0.25f : 1.0f;
        unsigned short* o = o16 + (size_t)a * ((size_t)NROWS * 128)
                          + (size_t)r0 * 128 + (gc0 & 127) + cg * 4;
        #pragma unroll
        for (int i = 0; i < 4; ++i) {
            uint2 pv;
            pv.x = (uint32_t)f2bf(acc[i][0] * scale) | ((uint32_t)f2bf(acc[i][1] * scale) << 16);
            pv.y = (uint32_t)f2bf(acc[i][2] * scale) | ((uint32_t)f2bf(acc[i][3] * scale) << 16);
            *(uint2*)(o + (size_t)(rg * 4 + i) * 128) = pv;
        }
    } else {
        float* o = (float*)outp + (size_t)r0 * 128 + gc0;
        #pragma unroll
        for (int i = 0; i < 4; ++i) {
            float4 v = { acc[i][0], acc[i][1], acc[i][2], acc[i][3] };
            if (relu) {
                v.x = fmaxf(v.x, 0.f); v.y = fmaxf(v.y, 0.f);
                v.z = fmaxf(v.z, 0.f); v.w = fmaxf(v.w, 0.f);
            }
            *(float4*)(o + (size_t)(rg * 4 + i) * 128 + cg * 4) = v;
        }
    }
}

// ---------------------------------------------------------------- MFMA flash attention + fused LN1
// Block: (b, 32 q-rows) x all 8 heads; 4 waves x 2 heads. KB=32 keys/step.
// QK^T swapped (mfma 32x32x16: A=K, B=Q) -> lane owns one q column.
// PV: mfma 16x16x32, A=P (LDS, 80B rows), B=V via scalar u16 LDS reads
//     from [key][d] tiles (36B rows, 1156B head stride -> 2-way banks).
// Epilogue: ctx -> LDS fp32, then LN1(x + ctx) -> x1 (fp32).
//
// LDS map (bytes):
//   sK [0, 8192)        : [32 keys][16 slots x 16B], slot XOR-swizzled
//   sV [8192, 17440)    : 8 heads x (32 keys x 18 shorts = 1152B, stride 1156)
//   sP [17440, 37920)   : 8 x [32 q][40 shorts] bf16 (80B rows, 2560B each)
//   sM [37920, 38048)   : [32 q] x 4 keep-bit bytes
//   sS [38048, 39072)   : 8 x [32] f32 scale/inv
//   epilogue: sC = smem [0, 16896) fp32 [32][132]
__global__ __launch_bounds__(256, 2) void k_attn(
        const unsigned short* __restrict__ qb,
        const unsigned short* __restrict__ kb,
        const unsigned short* __restrict__ vbp,
        const void* __restrict__ maskp, const int* __restrict__ flag,
        const float* __restrict__ x, const float* __restrict__ g1,
        const float* __restrict__ be1, float* __restrict__ x1)
{
    __shared__ alignas(16) char smem[39072];
    char*          const sK = smem;
    char*          const sV = smem + 8192;
    char*          const sP = smem + 17440;
    unsigned char* const sM = (unsigned char*)(smem + 37920);
    float*         const sS = (float*)(smem + 38048);

    const int t  = threadIdx.x;
    const int w  = t >> 6;
    const int l  = t & 63;
    const int b  = blockIdx.y;
    const int q0 = blockIdx.x * 32;
    const int q   = l & 31;
    const int hi  = l >> 5;
    const int l4  = l >> 4;
    const int l15 = l & 15;
    const int bytemask = *flag;

    short8 qf0, qf1;
    {
        const size_t qrow = (size_t)(b * 1024 + q0 + q) * 128;
        qf0 = *(const short8*)(qb + qrow + (2 * w + 0) * 16 + hi * 8);
        qf1 = *(const short8*)(qb + qrow + (2 * w + 1) * 16 + hi * 8);
    }
    float m0 = -INFINITY, m1 = -INFINITY;
    float ls0 = 0.f, ls1 = 0.f;
    f32x4 a00 = {0,0,0,0}, a01 = {0,0,0,0}, a10 = {0,0,0,0}, a11 = {0,0,0,0};
    const f32x16 z16 = {};
    float* const sS0 = sS + (w * 2 + 0) * 32;
    float* const sS1 = sS + (w * 2 + 1) * 32;
    char*  const sP0 = sP + (w * 2 + 0) * 2560;
    char*  const sP1 = sP + (w * 2 + 1) * 2560;

    const uint8_t* m8  = (const uint8_t*)maskp;
    const int*     m32 = (const int*)maskp;

    uint32_t mks = 0;

    auto head_step = [&](int h, short8 qf, float& m, float& ls,
                         f32x4& ac0, f32x4& ac1, float* sSw, char* Pw) {
        // A fragment = K: row=key=q(lane&31), k-elems = hd (2h+hi)*8..+7 (swizzled slot)
        short8 kf = *(const short8*)(sK + q * 256 + ((((h << 1) + hi) ^ (q & 15)) << 4));
        f32x16 sc = __builtin_amdgcn_mfma_f32_32x32x16_bf16(kf, qf, z16, 0, 0, 0);
        // step max over this lane's 16 keys + partner half
        float sm = sc[0];
        #pragma unroll
        for (int r = 1; r < 16; ++r) sm = fmaxf(sm, sc[r]);
        sm = fmaxf(sm, __shfl_xor(sm, 32));
        if (__any(sm > m + 8.f)) {             // defer-max (THR=8)
            float nm = fmaxf(m, sm);
            float s  = __expf(m - nm);
            m = nm; ls *= s;
            sSw[q] = s;                        // lanes l and l^32 write same value
            float4 s0v = *(float4*)&sSw[l4 * 4];
            float4 s1v = *(float4*)&sSw[l4 * 4 + 16];
            ac0[0] *= s0v.x; ac0[1] *= s0v.y; ac0[2] *= s0v.z; ac0[3] *= s0v.w;
            ac1[0] *= s1v.x; ac1[1] *= s1v.y; ac1[2] *= s1v.z; ac1[3] *= s1v.w;
        }
        float p[16]; float lsum = 0.f;
        #pragma unroll
        for (int r = 0; r < 16; ++r) {
            const int c = (r & 3) + 8 * (r >> 2);       // key = c + 4*hi
            float pv = __expf(sc[r] - m);
            pv = ((mks >> c) & 1u) ? pv : 0.f;          // multiplicative mask
            lsum += pv; p[r] = pv;
        }
        ls += lsum;
        // pack P -> bf16 LDS [32 q][40 shorts] (80B rows, 16B-aligned)
        #pragma unroll
        for (int g = 0; g < 4; ++g) {
            uint2 pk;
            pk.x = (uint32_t)f2bf(p[4*g+0]) | ((uint32_t)f2bf(p[4*g+1]) << 16);
            pk.y = (uint32_t)f2bf(p[4*g+2]) | ((uint32_t)f2bf(p[4*g+3]) << 16);
            *(uint2*)(Pw + q * 80 + (8 * g + 4 * hi) * 2) = pk;
        }
        // PV: A = P rows l15 / l15+16, keys l4*8..+7 (b128, aligned)
        short8 pa0 = *(const short8*)(Pw + l15 * 80 + l4 * 16);
        short8 pa1 = *(const short8*)(Pw + (l15 + 16) * 80 + l4 * 16);
        // B = V[key][d]: lane holds keys l4*8..+7 at d=l15 (scalar u16 reads, 2-way banks)
        const unsigned short* sVh = (const unsigned short*)(sV + h * 1156);
        short8 vf;
        #pragma unroll
        for (int j = 0; j < 8; ++j)
            vf[j] = (short)sVh[(l4 * 8 + j) * 18 + l15];
        ac0 = __builtin_amdgcn_mfma_f32_16x16x32_bf16(pa0, vf, ac0, 0, 0, 0);
        ac1 = __builtin_amdgcn_mfma_f32_16x16x32_bf16(pa1, vf, ac1, 0, 0, 0);
    };

    for (int kt = 0; kt < 32; ++kt) {
        const int k0 = kt * 32;
        __syncthreads();
        // ---- stage K (XOR-swizzled 16B slots) and V (per-head [32][18] short tiles) ----
        #pragma unroll
        for (int i = 0; i < 2; ++i) {
            const int idx = t + 256 * i;                // 16B chunk id, 0..511
            const int row = idx >> 4, slot = idx & 15;
            const size_t src = (size_t)(b * 1024 + k0 + row) * 128 + slot * 8;
            uint4 kv = *(const uint4*)(kb + src);
            *(uint4*)(sK + row * 256 + ((slot ^ (row & 15)) << 4)) = kv;
            uint4 vv = *(const uint4*)(vbp + src);
            unsigned short* dh = (unsigned short*)(sV + (slot >> 1) * 1156);
            uint32_t* dst = (uint32_t*)(dh + row * 18 + (slot & 1) * 8);  // 4B-aligned
            dst[0] = vv.x; dst[1] = vv.y; dst[2] = vv.z; dst[3] = vv.w;
        }
        // ---- stage mask keep-bits: [32 q] x 32 keys (4 bytes/q) ----
        {
            const int mq = t >> 3, g = t & 7;
            if (g < 4) {
                const size_t moff = ((size_t)b << 20) + (size_t)(q0 + mq) * 1024
                                  + (size_t)(k0 + g * 8);
                unsigned int bits = 0;
                if (bytemask) {
                    uint64_t v = *(const uint64_t*)(m8 + moff);
                    #pragma unroll
                    for (int j = 0; j < 8; ++j)
                        bits |= ((((v >> (8 * j)) & 0xffull) == 0ull) ? 1u : 0u) << j;
                } else {
                    const int4* p = (const int4*)(m32 + moff);
                    int4 va = p[0], vc = p[1];
                    bits = (va.x==0?1u:0u) | (va.y==0?2u:0u) | (va.z==0?4u:0u) | (va.w==0?8u:0u)
                         | (vc.x==0?16u:0u) | (vc.y==0?32u:0u) | (vc.z==0?64u:0u) | (vc.w==0?128u:0u);
                }
                sM[mq * 4 + g] = (unsigned char)bits;
            }
        }
        __syncthreads();

        const uint32_t mk = *(const uint32_t*)(sM + q * 4);
        mks = mk >> (4 * hi);

        head_step(2 * w + 0, qf0, m0, ls0, a00, a01, sS0, sP0);
        head_step(2 * w + 1, qf1, m1, ls1, a10, a11, sS1, sP1);
    }

    __syncthreads();
    // ---- epilogue: normalize, ctx -> LDS fp32 [32][132] ----
    float* const sC = (float*)smem;
    auto finish = [&](int h, float ls, f32x4 ac0, f32x4 ac1, float* sSw) {
        float lt  = ls + __shfl_xor(ls, 32);
        float inv = 1.f / lt;
        sSw[q] = inv;
        float4 i0 = *(float4*)&sSw[l4 * 4];
        float4 i1 = *(float4*)&sSw[l4 * 4 + 16];
        const int cc = h * 16 + l15;
        sC[(l4 * 4 + 0) * 132 + cc]  = ac0[0] * i0.x;
        sC[(l4 * 4 + 1) * 132 + cc]  = ac0[1] * i0.y;
        sC[(l4 * 4 + 2) * 132 + cc]  = ac0[2] * i0.z;
        sC[(l4 * 4 + 3) * 132 + cc]  = ac0[3] * i0.w;
        sC[(l4 * 4 + 16) * 132 + cc] = ac1[0] * i1.x;
        sC[(l4 * 4 + 17) * 132 + cc] = ac1[1] * i1.y;
        sC[(l4 * 4 + 18) * 132 + cc] = ac1[2] * i1.z;
        sC[(l4 * 4 + 19) * 132 + cc] = ac1[3] * i1.w;
    };
    finish(2 * w + 0, ls0, a00, a01, sS0);
    finish(2 * w + 1, ls1, a10, a11, sS1);
    __syncthreads();

    // ---- fused LN1: x1 = LN(x + ctx); wave w owns rows 8w..8w+7, 8 lanes/row ----
    {
        const int row = w * 8 + (l >> 3);
        const int c0  = (l & 7) * 16;
        const size_t grow = (size_t)(b * 1024 + q0 + row);
        const float4* xp = (const float4*)(x + grow * 128 + c0);
        const float4* cp = (const float4*)(sC + row * 132 + c0);
        float y[16];
        float s = 0.f;
        #pragma unroll
        for (int j = 0; j < 4; ++j) {
            float4 xv = xp[j], cv = cp[j];
            y[4*j+0] = xv.x + cv.x; y[4*j+1] = xv.y + cv.y;
            y[4*j+2] = xv.z + cv.z; y[4*j+3] = xv.w + cv.w;
            s += y[4*j+0] + y[4*j+1] + y[4*j+2] + y[4*j+3];
        }
        s += __shfl_xor(s, 1); s += __shfl_xor(s, 2); s += __shfl_xor(s, 4);
        const float mu = s * (1.f / 128.f);
        float vv = 0.f;
        #pragma unroll
        for (int e = 0; e < 16; ++e) { float d = y[e] - mu; vv += d * d; }
        vv += __shfl_xor(vv, 1); vv += __shfl_xor(vv, 2); vv += __shfl_xor(vv, 4);
        const float rs = rsqrtf(vv * (1.f / 128.f) + 1e-5f);
        #pragma unroll
        for (int j = 0; j < 4; ++j) {
            float4 gv = *(const float4*)(g1 + c0 + 4 * j);
            float4 bv = *(const float4*)(be1 + c0 + 4 * j);
            float4 o;
            o.x = (y[4*j+0] - mu) * rs * gv.x + bv.x;
            o.y = (y[4*j+1] - mu) * rs * gv.y + bv.y;
            o.z = (y[4*j+2] - mu) * rs * gv.z + bv.z;
            o.w = (y[4*j+3] - mu) * rs * gv.w + bv.w;
            *(float4*)(x1 + grow * 128 + c0 + 4 * j) = o;
        }
    }
}

// ---------------------------------------------------------------- GEMM2 + LN2 (unchanged)
__global__ __launch_bounds__(256, 2) void k_gemm2(const float* __restrict__ h1,
        const float* __restrict__ w2, const float* __restrict__ b2,
        const float* __restrict__ x1, const float* __restrict__ g2,
        const float* __restrict__ be2, float* __restrict__ out)
{
    __shared__ float Ht[64][68];
    __shared__ float Wt[64][128];
    __shared__ float red[64][17];
    __shared__ float meanv[64];
    __shared__ float rsv[64];
    const int r0 = blockIdx.x * 64;
    const int t  = threadIdx.x;
    const int rg = t >> 4;
    const int cg = t & 15;

    float acc[4][8];
    {
        float4 ba = *(const float4*)(b2 + cg * 8);
        float4 bb = *(const float4*)(b2 + cg * 8 + 4);
        #pragma unroll
        for (int i = 0; i < 4; ++i) {
            acc[i][0]=ba.x; acc[i][1]=ba.y; acc[i][2]=ba.z; acc[i][3]=ba.w;
            acc[i][4]=bb.x; acc[i][5]=bb.y; acc[i][6]=bb.z; acc[i][7]=bb.w;
        }
    }
    for (int kt = 0; kt < 2; ++kt) {
        __syncthreads();
        #pragma unroll
        for (int i = 0; i < 4; ++i) {
            int e = t + 256 * i;
            int r = e >> 4, c4 = e & 15;
            *(float4*)&Ht[r][c4 * 4] =
                *(const float4*)(h1 + (size_t)(r0 + r) * 128 + kt * 64 + c4 * 4);
        }
        #pragma unroll
        for (int i = 0; i < 8; ++i) {
            int e = t + 256 * i;
            int k = e >> 5, c4 = e & 31;
            *(float4*)&Wt[k][c4 * 4] =
                *(const float4*)(w2 + (size_t)(kt * 64 + k) * 128 + c4 * 4);
        }
        __syncthreads();
        #pragma unroll 4
        for (int k = 0; k < 64; ++k) {
            float hv[4];
            #pragma unroll
            for (int i = 0; i < 4; ++i) hv[i] = Ht[rg * 4 + i][k];
            float4 w0 = *(const float4*)&Wt[k][cg * 8];
            float4 w1 = *(const float4*)&Wt[k][cg * 8 + 4];
            #pragma unroll
            for (int i = 0; i < 4; ++i) {
                acc[i][0] += hv[i] * w0.x; acc[i][1] += hv[i] * w0.y;
                acc[i][2] += hv[i] * w0.z; acc[i][3] += hv[i] * w0.w;
                acc[i][4] += hv[i] * w1.x; acc[i][5] += hv[i] * w1.y;
                acc[i][6] += hv[i] * w1.z; acc[i][7] += hv[i] * w1.w;
            }
        }
    }
    float y[4][8];
    #pragma unroll
    for (int i = 0; i < 4; ++i) {
        float4 xa = *(const float4*)(x1 + (size_t)(r0 + rg * 4 + i) * 128 + cg * 8);
        float4 xb = *(const float4*)(x1 + (size_t)(r0 + rg * 4 + i) * 128 + cg * 8 + 4);
        y[i][0]=xa.x+acc[i][0]; y[i][1]=xa.y+acc[i][1]; y[i][2]=xa.z+acc[i][2]; y[i][3]=xa.w+acc[i][3];
        y[i][4]=xb.x+acc[i][4]; y[i][5]=xb.y+acc[i][5]; y[i][6]=xb.z+acc[i][6]; y[i][7]=xb.w+acc[i][7];
    }
    __syncthreads();
    #pragma unroll
    for (int i = 0; i < 4; ++i) {
        float s = 0.f;
        #pragma unroll
        for (int j = 0; j < 8; ++j) s += y[i][j];
        red[rg * 4 + i][cg] = s;
    }
    __syncthreads();
    if (t < 64) {
        float s = 0.f;
        #pragma unroll
        for (int j = 0; j < 16; ++j) s += red[t][j];
        meanv[t] = s * (1.f / 128.f);
    }
    __syncthreads();
    #pragma unroll
    for (int i = 0; i < 4; ++i) {
        float mu = meanv[rg * 4 + i];
        float s = 0.f;
        #pragma unroll
        for (int j = 0; j < 8; ++j) { float d = y[i][j] - mu; s += d * d; }
        red[rg * 4 + i][cg] = s;
    }
    __syncthreads();
    if (t < 64) {
        float s = 0.f;
        #pragma unroll
        for (int j = 0; j < 16; ++j) s += red[t][j];
        rsv[t] = rsqrtf(s * (1.f / 128.f) + 1e-5f);
    }
    __syncthreads();
    float4 ga = *(const float4*)(g2 + cg * 8);
    float4 gb = *(const float4*)(g2 + cg * 8 + 4);
    float4 ba = *(const float4*)(be2 + cg * 8);
    float4 bb = *(const float4*)(be2 + cg * 8 + 4);
    #pragma unroll
    for (int i = 0; i < 4; ++i) {
        int r = r0 + rg * 4 + i;
        float mu = meanv[rg * 4 + i], rs = rsv[rg * 4 + i];
        float4 o0 = { (y[i][0]-mu)*rs*ga.x + ba.x, (y[i][1]-mu)*rs*ga.y + ba.y,
                      (y[i][2]-mu)*rs*ga.z + ba.z, (y[i][3]-mu)*rs*ga.w + ba.w };
        float4 o1 = { (y[i][4]-mu)*rs*gb.x + bb.x, (y[i][5]-mu)*rs*gb.y + bb.y,
                      (y[i][6]-mu)*rs*gb.z + bb.z, (y[i][7]-mu)*rs*gb.w + bb.w };
        *(float4*)(out + (size_t)r * 128 + cg * 8)     = o0;
        *(float4*)(out + (size_t)r * 128 + cg * 8 + 4) = o1;
    }
}

// ---------------------------------------------------------------- launch
extern "C" void kernel_launch(void* const* d_in, const int* in_sizes, int n_in,
                              void* d_out, int out_size, void* d_ws, size_t ws_size,
                              hipStream_t stream)
{
    const float* x    = (const float*)d_in[0];
    const void*  mask = d_in[1];
    const float* wqkv = (const float*)d_in[2];
    const float* bqkv = (const float*)d_in[3];
    const float* w1   = (const float*)d_in[4];
    const float* b1   = (const float*)d_in[5];
    const float* w2   = (const float*)d_in[6];
    const float* b2   = (const float*)d_in[7];
    const float* g1   = (const float*)d_in[8];
    const float* be1  = (const float*)d_in[9];
    const float* g2   = (const float*)d_in[10];
    const float* be2  = (const float*)d_in[11];
    float* out = (float*)d_out;

    char* base = (char*)d_ws;
    int* flag = (int*)base;
    unsigned short* qb = (unsigned short*)(base + 256);                    // 4MB
    unsigned short* kb = qb + (size_t)NROWS * 128;                         // 4MB
    unsigned short* vb = kb + (size_t)NROWS * 128;                         // 4MB
    float* h1 = (float*)(base + 256 + (size_t)4  * 1024 * 1024);           // overlays kb,vb (dead post-attn)
    float* x1 = (float*)(base + 256 + (size_t)12 * 1024 * 1024);           // 8MB

    k_detect<<<1, 64, 0, stream>>>((const uint32_t*)mask, flag);
    k_gemm<<<dim3(256, 6), 256, 0, stream>>>(x, wqkv, bqkv, (void*)qb, 384, 0, 1);
    k_attn<<<dim3(32, 16), 256, 0, stream>>>(qb, kb, vb, mask, flag, x, g1, be1, x1);
    k_gemm<<<dim3(256, 2), 256, 0, stream>>>(x1, w1, b1, (void*)h1, 128, 1, 0);
    k_gemm2<<<256, 256, 0, stream>>>(h1, w2, b2, x1, g2, be2, out);
}

// Round 6
// 211.386 us; speedup vs baseline: 2.0898x; 1.1550x over previous
//
#include <hip/hip_runtime.h>
#include <cstdint>

#define NROWS 16384
#define ARRE ((size_t)NROWS * 128)

typedef short short8 __attribute__((ext_vector_type(8)));
typedef float f32x4  __attribute__((ext_vector_type(4)));
typedef float f32x16 __attribute__((ext_vector_type(16)));

static __device__ __forceinline__ unsigned short f2bf(float f) {
    union { float f; uint32_t u; } v; v.f = f;
    uint32_t r = v.u + 0x7fffu + ((v.u >> 16) & 1u);   // RNE
    return (unsigned short)(r >> 16);
}

// ---------------------------------------------------------------- detect mask encoding
__global__ void k_detect(const uint32_t* __restrict__ m, int* __restrict__ flag) {
    if (threadIdx.x == 0) {
        int f = 0;
        for (int i = 0; i < 256; ++i) f |= (m[i] > 1u) ? 1 : 0;
        *flag = f;   // 1 => byte-encoded bool mask, 0 => int32 mask
    }
}

// ---------------------------------------------------------------- weights -> bf16 transposed
// wT layout: [0,49152) wqkvT[384][128]; [49152,65536) w1T[128][128]; [65536,81920) w2T
__global__ void k_castw(const float* __restrict__ wqkv, const float* __restrict__ w1,
                        const float* __restrict__ w2, unsigned short* __restrict__ wT)
{
    const int e = blockIdx.x * 256 + threadIdx.x;
    if (e < 49152) {
        const int n = e >> 7, k = e & 127;
        wT[e] = f2bf(wqkv[k * 384 + n]);
    } else if (e < 65536) {
        const int i = e - 49152, n = i >> 7, k = i & 127;
        wT[e] = f2bf(w1[k * 128 + n]);
    } else if (e < 81920) {
        const int i = e - 65536, n = i >> 7, k = i & 127;
        wT[e] = f2bf(w2[k * 128 + n]);
    }
}

// ---------------------------------------------------------------- MFMA GEMM (K=128, 64 rows x NF*16 cols)
// A = Xf (fp32, converted to bf16 while staging), B = Wt (bf16, pre-transposed [n][k]).
// Fragment layout identical to the verified attn PV path.
// MODE 0: QKV -> bf16 3-array chunked out, col>>7 selects array, array 0 scaled 0.25.
// MODE 1: FFN1 -> relu, bf16 out [row][128].
template<int NF, int MODE>
__global__ __launch_bounds__(256, 2) void k_mm(const float* __restrict__ Xf,
        const unsigned short* __restrict__ Wt, const float* __restrict__ bias,
        unsigned short* __restrict__ out)
{
    __shared__ char smem[16384 + NF * 4096];
    char* const sX = smem;
    char* const sW = smem + 16384;
    const int t = threadIdx.x;
    const int w = t >> 6, l = t & 63;
    const int l4 = l >> 4, l15 = l & 15;
    const int r0 = blockIdx.x * 64;
    const int c0 = blockIdx.y * (NF * 16);

    // stage X: 64 rows x 128 k, fp32 -> bf16, 16B slots XOR-swizzled by row
    #pragma unroll
    for (int i = 0; i < 4; ++i) {
        const int c = t + 256 * i;
        const int row = c >> 4, slot = c & 15;
        const float4* src = (const float4*)(Xf + (size_t)(r0 + row) * 128 + slot * 8);
        float4 f0 = src[0], f1 = src[1];
        uint4 v;
        v.x = (uint32_t)f2bf(f0.x) | ((uint32_t)f2bf(f0.y) << 16);
        v.y = (uint32_t)f2bf(f0.z) | ((uint32_t)f2bf(f0.w) << 16);
        v.z = (uint32_t)f2bf(f1.x) | ((uint32_t)f2bf(f1.y) << 16);
        v.w = (uint32_t)f2bf(f1.z) | ((uint32_t)f2bf(f1.w) << 16);
        *(uint4*)(sX + row * 256 + ((slot ^ (row & 15)) << 4)) = v;
    }
    // stage W^T: NF*16 cols x 128 k (bf16 direct copy, same swizzle)
    #pragma unroll
    for (int i = 0; i < NF; ++i) {
        const int c = t + 256 * i;
        const int col = c >> 4, slot = c & 15;
        uint4 v = *(const uint4*)(Wt + (size_t)(c0 + col) * 128 + slot * 8);
        *(uint4*)(sW + col * 256 + ((slot ^ (col & 15)) << 4)) = v;
    }
    __syncthreads();

    short8 aF[4];
    #pragma unroll
    for (int kk = 0; kk < 4; ++kk)
        aF[kk] = *(const short8*)(sX + (w * 16 + l15) * 256 + (((kk * 4 + l4) ^ l15) << 4));

    f32x4 acc[NF];
    #pragma unroll
    for (int nf = 0; nf < NF; ++nf) acc[nf] = f32x4{0.f, 0.f, 0.f, 0.f};
    #pragma unroll
    for (int nf = 0; nf < NF; ++nf) {
        #pragma unroll
        for (int kk = 0; kk < 4; ++kk) {
            short8 bF = *(const short8*)(sW + (nf * 16 + l15) * 256 + (((kk * 4 + l4) ^ l15) << 4));
            acc[nf] = __builtin_amdgcn_mfma_f32_16x16x32_bf16(aF[kk], bF, acc[nf], 0, 0, 0);
        }
    }

    const float scl = (MODE == 0 && blockIdx.y == 0) ? 0.25f : 1.0f;
    #pragma unroll
    for (int nf = 0; nf < NF; ++nf) {
        const int col = c0 + nf * 16 + l15;
        const float bv = bias[col];
        #pragma unroll
        for (int reg = 0; reg < 4; ++reg) {
            float v = acc[nf][reg] + bv;
            if (MODE == 1) v = fmaxf(v, 0.f);
            v *= scl;
            const int row = r0 + w * 16 + l4 * 4 + reg;
            size_t o;
            if (MODE == 0) o = (size_t)(col >> 7) * ARRE + (size_t)row * 128 + (col & 127);
            else           o = (size_t)row * 128 + col;
            out[o] = f2bf(v);
        }
    }
}

// ---------------------------------------------------------------- MFMA GEMM2 + residual + LN2 -> fp32 out
__global__ __launch_bounds__(256, 2) void k_mm2(const unsigned short* __restrict__ h1,
        const unsigned short* __restrict__ w2t, const float* __restrict__ b2,
        const float* __restrict__ x1, const float* __restrict__ g2,
        const float* __restrict__ be2, float* __restrict__ out)
{
    __shared__ char smem[16384 + 32768];
    char* const sX = smem;
    char* const sW = smem + 16384;
    const int t = threadIdx.x;
    const int w = t >> 6, l = t & 63;
    const int l4 = l >> 4, l15 = l & 15;
    const int r0 = blockIdx.x * 64;

    #pragma unroll
    for (int i = 0; i < 4; ++i) {
        const int c = t + 256 * i;
        const int row = c >> 4, slot = c & 15;
        uint4 v = *(const uint4*)(h1 + (size_t)(r0 + row) * 128 + slot * 8);
        *(uint4*)(sX + row * 256 + ((slot ^ (row & 15)) << 4)) = v;
    }
    #pragma unroll
    for (int i = 0; i < 8; ++i) {
        const int c = t + 256 * i;
        const int col = c >> 4, slot = c & 15;
        uint4 v = *(const uint4*)(w2t + (size_t)col * 128 + slot * 8);
        *(uint4*)(sW + col * 256 + ((slot ^ (col & 15)) << 4)) = v;
    }
    __syncthreads();

    short8 aF[4];
    #pragma unroll
    for (int kk = 0; kk < 4; ++kk)
        aF[kk] = *(const short8*)(sX + (w * 16 + l15) * 256 + (((kk * 4 + l4) ^ l15) << 4));

    f32x4 acc[8];
    #pragma unroll
    for (int nf = 0; nf < 8; ++nf) acc[nf] = f32x4{0.f, 0.f, 0.f, 0.f};
    #pragma unroll
    for (int nf = 0; nf < 8; ++nf) {
        #pragma unroll
        for (int kk = 0; kk < 4; ++kk) {
            short8 bF = *(const short8*)(sW + (nf * 16 + l15) * 256 + (((kk * 4 + l4) ^ l15) << 4));
            acc[nf] = __builtin_amdgcn_mfma_f32_16x16x32_bf16(aF[kk], bF, acc[nf], 0, 0, 0);
        }
    }

    // epilogue: y = acc + b2 + x1 ; LN2 per row (rows owned by l4*4+reg, 16 l15-lanes/row)
    float b2c[8], g2c[8], bec[8];
    #pragma unroll
    for (int nf = 0; nf < 8; ++nf) {
        const int col = nf * 16 + l15;
        b2c[nf] = b2[col]; g2c[nf] = g2[col]; bec[nf] = be2[col];
    }
    float y[8][4];
    #pragma unroll
    for (int nf = 0; nf < 8; ++nf) {
        const int col = nf * 16 + l15;
        #pragma unroll
        for (int reg = 0; reg < 4; ++reg) {
            const int row = r0 + w * 16 + l4 * 4 + reg;
            y[nf][reg] = acc[nf][reg] + b2c[nf] + x1[(size_t)row * 128 + col];
        }
    }
    #pragma unroll
    for (int reg = 0; reg < 4; ++reg) {
        float s = 0.f;
        #pragma unroll
        for (int nf = 0; nf < 8; ++nf) s += y[nf][reg];
        s += __shfl_xor(s, 1); s += __shfl_xor(s, 2);
        s += __shfl_xor(s, 4); s += __shfl_xor(s, 8);
        const float mu = s * (1.f / 128.f);
        float vv = 0.f;
        #pragma unroll
        for (int nf = 0; nf < 8; ++nf) { float d = y[nf][reg] - mu; vv += d * d; }
        vv += __shfl_xor(vv, 1); vv += __shfl_xor(vv, 2);
        vv += __shfl_xor(vv, 4); vv += __shfl_xor(vv, 8);
        const float rs = rsqrtf(vv * (1.f / 128.f) + 1e-5f);
        const int row = r0 + w * 16 + l4 * 4 + reg;
        #pragma unroll
        for (int nf = 0; nf < 8; ++nf) {
            const int col = nf * 16 + l15;
            out[(size_t)row * 128 + col] = (y[nf][reg] - mu) * rs * g2c[nf] + bec[nf];
        }
    }
}

// ---------------------------------------------------------------- MFMA flash attention + fused LN1 (unchanged)
__global__ __launch_bounds__(256, 2) void k_attn(
        const unsigned short* __restrict__ qb,
        const unsigned short* __restrict__ kb,
        const unsigned short* __restrict__ vbp,
        const void* __restrict__ maskp, const int* __restrict__ flag,
        const float* __restrict__ x, const float* __restrict__ g1,
        const float* __restrict__ be1, float* __restrict__ x1)
{
    __shared__ alignas(16) char smem[39072];
    char*          const sK = smem;
    char*          const sV = smem + 8192;
    char*          const sP = smem + 17440;
    unsigned char* const sM = (unsigned char*)(smem + 37920);
    float*         const sS = (float*)(smem + 38048);

    const int t  = threadIdx.x;
    const int w  = t >> 6;
    const int l  = t & 63;
    const int b  = blockIdx.y;
    const int q0 = blockIdx.x * 32;
    const int q   = l & 31;
    const int hi  = l >> 5;
    const int l4  = l >> 4;
    const int l15 = l & 15;
    const int bytemask = *flag;

    short8 qf0, qf1;
    {
        const size_t qrow = (size_t)(b * 1024 + q0 + q) * 128;
        qf0 = *(const short8*)(qb + qrow + (2 * w + 0) * 16 + hi * 8);
        qf1 = *(const short8*)(qb + qrow + (2 * w + 1) * 16 + hi * 8);
    }
    float m0 = -INFINITY, m1 = -INFINITY;
    float ls0 = 0.f, ls1 = 0.f;
    f32x4 a00 = {0,0,0,0}, a01 = {0,0,0,0}, a10 = {0,0,0,0}, a11 = {0,0,0,0};
    const f32x16 z16 = {};
    float* const sS0 = sS + (w * 2 + 0) * 32;
    float* const sS1 = sS + (w * 2 + 1) * 32;
    char*  const sP0 = sP + (w * 2 + 0) * 2560;
    char*  const sP1 = sP + (w * 2 + 1) * 2560;

    const uint8_t* m8  = (const uint8_t*)maskp;
    const int*     m32 = (const int*)maskp;

    uint32_t mks = 0;

    auto head_step = [&](int h, short8 qf, float& m, float& ls,
                         f32x4& ac0, f32x4& ac1, float* sSw, char* Pw) {
        short8 kf = *(const short8*)(sK + q * 256 + ((((h << 1) + hi) ^ (q & 15)) << 4));
        f32x16 sc = __builtin_amdgcn_mfma_f32_32x32x16_bf16(kf, qf, z16, 0, 0, 0);
        float sm = sc[0];
        #pragma unroll
        for (int r = 1; r < 16; ++r) sm = fmaxf(sm, sc[r]);
        sm = fmaxf(sm, __shfl_xor(sm, 32));
        if (__any(sm > m + 8.f)) {             // defer-max (THR=8)
            float nm = fmaxf(m, sm);
            float s  = __expf(m - nm);
            m = nm; ls *= s;
            sSw[q] = s;
            float4 s0v = *(float4*)&sSw[l4 * 4];
            float4 s1v = *(float4*)&sSw[l4 * 4 + 16];
            ac0[0] *= s0v.x; ac0[1] *= s0v.y; ac0[2] *= s0v.z; ac0[3] *= s0v.w;
            ac1[0] *= s1v.x; ac1[1] *= s1v.y; ac1[2] *= s1v.z; ac1[3] *= s1v.w;
        }
        float p[16]; float lsum = 0.f;
        #pragma unroll
        for (int r = 0; r < 16; ++r) {
            const int c = (r & 3) + 8 * (r >> 2);
            float pv = __expf(sc[r] - m);
            pv = ((mks >> c) & 1u) ? pv : 0.f;
            lsum += pv; p[r] = pv;
        }
        ls += lsum;
        #pragma unroll
        for (int g = 0; g < 4; ++g) {
            uint2 pk;
            pk.x = (uint32_t)f2bf(p[4*g+0]) | ((uint32_t)f2bf(p[4*g+1]) << 16);
            pk.y = (uint32_t)f2bf(p[4*g+2]) | ((uint32_t)f2bf(p[4*g+3]) << 16);
            *(uint2*)(Pw + q * 80 + (8 * g + 4 * hi) * 2) = pk;
        }
        short8 pa0 = *(const short8*)(Pw + l15 * 80 + l4 * 16);
        short8 pa1 = *(const short8*)(Pw + (l15 + 16) * 80 + l4 * 16);
        const unsigned short* sVh = (const unsigned short*)(sV + h * 1156);
        short8 vf;
        #pragma unroll
        for (int j = 0; j < 8; ++j)
            vf[j] = (short)sVh[(l4 * 8 + j) * 18 + l15];
        ac0 = __builtin_amdgcn_mfma_f32_16x16x32_bf16(pa0, vf, ac0, 0, 0, 0);
        ac1 = __builtin_amdgcn_mfma_f32_16x16x32_bf16(pa1, vf, ac1, 0, 0, 0);
    };

    for (int kt = 0; kt < 32; ++kt) {
        const int k0 = kt * 32;
        __syncthreads();
        #pragma unroll
        for (int i = 0; i < 2; ++i) {
            const int idx = t + 256 * i;
            const int row = idx >> 4, slot = idx & 15;
            const size_t src = (size_t)(b * 1024 + k0 + row) * 128 + slot * 8;
            uint4 kv = *(const uint4*)(kb + src);
            *(uint4*)(sK + row * 256 + ((slot ^ (row & 15)) << 4)) = kv;
            uint4 vv = *(const uint4*)(vbp + src);
            unsigned short* dh = (unsigned short*)(sV + (slot >> 1) * 1156);
            uint32_t* dst = (uint32_t*)(dh + row * 18 + (slot & 1) * 8);
            dst[0] = vv.x; dst[1] = vv.y; dst[2] = vv.z; dst[3] = vv.w;
        }
        {
            const int mq = t >> 3, g = t & 7;
            if (g < 4) {
                const size_t moff = ((size_t)b << 20) + (size_t)(q0 + mq) * 1024
                                  + (size_t)(k0 + g * 8);
                unsigned int bits = 0;
                if (bytemask) {
                    uint64_t v = *(const uint64_t*)(m8 + moff);
                    #pragma unroll
                    for (int j = 0; j < 8; ++j)
                        bits |= ((((v >> (8 * j)) & 0xffull) == 0ull) ? 1u : 0u) << j;
                } else {
                    const int4* p = (const int4*)(m32 + moff);
                    int4 va = p[0], vc = p[1];
                    bits = (va.x==0?1u:0u) | (va.y==0?2u:0u) | (va.z==0?4u:0u) | (va.w==0?8u:0u)
                         | (vc.x==0?16u:0u) | (vc.y==0?32u:0u) | (vc.z==0?64u:0u) | (vc.w==0?128u:0u);
                }
                sM[mq * 4 + g] = (unsigned char)bits;
            }
        }
        __syncthreads();

        const uint32_t mk = *(const uint32_t*)(sM + q * 4);
        mks = mk >> (4 * hi);

        head_step(2 * w + 0, qf0, m0, ls0, a00, a01, sS0, sP0);
        head_step(2 * w + 1, qf1, m1, ls1, a10, a11, sS1, sP1);
    }

    __syncthreads();
    float* const sC = (float*)smem;
    auto finish = [&](int h, float ls, f32x4 ac0, f32x4 ac1, float* sSw) {
        float lt  = ls + __shfl_xor(ls, 32);
        float inv = 1.f / lt;
        sSw[q] = inv;
        float4 i0 = *(float4*)&sSw[l4 * 4];
        float4 i1 = *(float4*)&sSw[l4 * 4 + 16];
        const int cc = h * 16 + l15;
        sC[(l4 * 4 + 0) * 132 + cc]  = ac0[0] * i0.x;
        sC[(l4 * 4 + 1) * 132 + cc]  = ac0[1] * i0.y;
        sC[(l4 * 4 + 2) * 132 + cc]  = ac0[2] * i0.z;
        sC[(l4 * 4 + 3) * 132 + cc]  = ac0[3] * i0.w;
        sC[(l4 * 4 + 16) * 132 + cc] = ac1[0] * i1.x;
        sC[(l4 * 4 + 17) * 132 + cc] = ac1[1] * i1.y;
        sC[(l4 * 4 + 18) * 132 + cc] = ac1[2] * i1.z;
        sC[(l4 * 4 + 19) * 132 + cc] = ac1[3] * i1.w;
    };
    finish(2 * w + 0, ls0, a00, a01, sS0);
    finish(2 * w + 1, ls1, a10, a11, sS1);
    __syncthreads();

    {
        const int row = w * 8 + (l >> 3);
        const int c0  = (l & 7) * 16;
        const size_t grow = (size_t)(b * 1024 + q0 + row);
        const float4* xp = (const float4*)(x + grow * 128 + c0);
        const float4* cp = (const float4*)(sC + row * 132 + c0);
        float y[16];
        float s = 0.f;
        #pragma unroll
        for (int j = 0; j < 4; ++j) {
            float4 xv = xp[j], cv = cp[j];
            y[4*j+0] = xv.x + cv.x; y[4*j+1] = xv.y + cv.y;
            y[4*j+2] = xv.z + cv.z; y[4*j+3] = xv.w + cv.w;
            s += y[4*j+0] + y[4*j+1] + y[4*j+2] + y[4*j+3];
        }
        s += __shfl_xor(s, 1); s += __shfl_xor(s, 2); s += __shfl_xor(s, 4);
        const float mu = s * (1.f / 128.f);
        float vv = 0.f;
        #pragma unroll
        for (int e = 0; e < 16; ++e) { float d = y[e] - mu; vv += d * d; }
        vv += __shfl_xor(vv, 1); vv += __shfl_xor(vv, 2); vv += __shfl_xor(vv, 4);
        const float rs = rsqrtf(vv * (1.f / 128.f) + 1e-5f);
        #pragma unroll
        for (int j = 0; j < 4; ++j) {
            float4 gv = *(const float4*)(g1 + c0 + 4 * j);
            float4 bv = *(const float4*)(be1 + c0 + 4 * j);
            float4 o;
            o.x = (y[4*j+0] - mu) * rs * gv.x + bv.x;
            o.y = (y[4*j+1] - mu) * rs * gv.y + bv.y;
            o.z = (y[4*j+2] - mu) * rs * gv.z + bv.z;
            o.w = (y[4*j+3] - mu) * rs * gv.w + bv.w;
            *(float4*)(x1 + grow * 128 + c0 + 4 * j) = o;
        }
    }
}

// ---------------------------------------------------------------- launch
extern "C" void kernel_launch(void* const* d_in, const int* in_sizes, int n_in,
                              void* d_out, int out_size, void* d_ws, size_t ws_size,
                              hipStream_t stream)
{
    const float* x    = (const float*)d_in[0];
    const void*  mask = d_in[1];
    const float* wqkv = (const float*)d_in[2];
    const float* bqkv = (const float*)d_in[3];
    const float* w1   = (const float*)d_in[4];
    const float* b1   = (const float*)d_in[5];
    const float* w2   = (const float*)d_in[6];
    const float* b2   = (const float*)d_in[7];
    const float* g1   = (const float*)d_in[8];
    const float* be1  = (const float*)d_in[9];
    const float* g2   = (const float*)d_in[10];
    const float* be2  = (const float*)d_in[11];
    float* out = (float*)d_out;

    char* base = (char*)d_ws;
    int* flag = (int*)base;
    unsigned short* qb  = (unsigned short*)(base + 256);                   // 4MB
    unsigned short* kb  = qb + ARRE;                                       // 4MB
    unsigned short* vb  = kb + ARRE;                                       // 4MB
    float* x1           = (float*)(base + 256 + (size_t)12 * 1024 * 1024); // 8MB
    unsigned short* wT  = (unsigned short*)(base + 256 + (size_t)20 * 1024 * 1024); // 160KB
    unsigned short* h1b = qb;   // overlays qb (dead after attn; stream-sequential)

    k_detect<<<1, 64, 0, stream>>>((const uint32_t*)mask, flag);
    k_castw<<<320, 256, 0, stream>>>(wqkv, w1, w2, wT);
    k_mm<8, 0><<<dim3(256, 3), 256, 0, stream>>>(x, wT, bqkv, qb);
    k_attn<<<dim3(32, 16), 256, 0, stream>>>(qb, kb, vb, mask, flag, x, g1, be1, x1);
    k_mm<4, 1><<<dim3(256, 2), 256, 0, stream>>>(x1, wT + 49152, b1, h1b);
    k_mm2<<<256, 256, 0, stream>>>(h1b, wT + 65536, b2, x1, g2, be2, out);
}

// Round 7
// 196.921 us; speedup vs baseline: 2.2433x; 1.0735x over previous
//
#include <hip/hip_runtime.h>
#include <cstdint>

#define NROWS 16384
#define ARRE ((size_t)NROWS * 128)

typedef short short8 __attribute__((ext_vector_type(8)));
typedef float f32x4  __attribute__((ext_vector_type(4)));
typedef float f32x16 __attribute__((ext_vector_type(16)));

static __device__ __forceinline__ unsigned short f2bf(float f) {
    union { float f; uint32_t u; } v; v.f = f;
    uint32_t r = v.u + 0x7fffu + ((v.u >> 16) & 1u);   // RNE
    return (unsigned short)(r >> 16);
}

static __device__ __forceinline__ uint32_t cvt_pk_bf16(float lo, float hi) {
    uint32_t r;
    asm("v_cvt_pk_bf16_f32 %0, %1, %2" : "=v"(r) : "v"(lo), "v"(hi));
    return r;
}

// ---------------------------------------------------------------- detect mask encoding
__global__ void k_detect(const uint32_t* __restrict__ m, int* __restrict__ flag) {
    if (threadIdx.x == 0) {
        int f = 0;
        for (int i = 0; i < 256; ++i) f |= (m[i] > 1u) ? 1 : 0;
        *flag = f;   // 1 => byte-encoded bool mask, 0 => int32 mask
    }
}

// ---------------------------------------------------------------- weights -> bf16 transposed
// wT layout: [0,49152) wqkvT[384][128]; [49152,65536) w1T[128][128]; [65536,81920) w2T
__global__ void k_castw(const float* __restrict__ wqkv, const float* __restrict__ w1,
                        const float* __restrict__ w2, unsigned short* __restrict__ wT)
{
    const int e = blockIdx.x * 256 + threadIdx.x;
    if (e < 49152) {
        const int n = e >> 7, k = e & 127;
        wT[e] = f2bf(wqkv[k * 384 + n]);
    } else if (e < 65536) {
        const int i = e - 49152, n = i >> 7, k = i & 127;
        wT[e] = f2bf(w1[k * 128 + n]);
    } else if (e < 81920) {
        const int i = e - 65536, n = i >> 7, k = i & 127;
        wT[e] = f2bf(w2[k * 128 + n]);
    }
}

// ---------------------------------------------------------------- MFMA GEMM (K=128, 64 rows x NF*16 cols)
// Swapped operands: mfma(A=W_frag, B=X_frag) -> D row = weight col (l4*4+reg),
// D col = X row (l15). Lane owns 4 consecutive output cols of one row ->
// vectorized uint2 bf16 stores.
// MODE 0: QKV -> bf16, blockIdx.y selects the Q/K/V array, Q scaled 0.25.
// MODE 1: FFN1 -> relu, bf16 out [row][128].
template<int NF, int MODE>
__global__ __launch_bounds__(256, 2) void k_mm(const float* __restrict__ Xf,
        const unsigned short* __restrict__ Wt, const float* __restrict__ bias,
        unsigned short* __restrict__ out)
{
    __shared__ char smem[16384 + NF * 4096];
    char* const sX = smem;
    char* const sW = smem + 16384;
    const int t = threadIdx.x;
    const int w = t >> 6, l = t & 63;
    const int l4 = l >> 4, l15 = l & 15;
    const int r0 = blockIdx.x * 64;
    const int c0 = blockIdx.y * (NF * 16);

    // stage X: 64 rows x 128 k, fp32 -> bf16, 16B slots XOR-swizzled by row
    #pragma unroll
    for (int i = 0; i < 4; ++i) {
        const int c = t + 256 * i;
        const int row = c >> 4, slot = c & 15;
        const float4* src = (const float4*)(Xf + (size_t)(r0 + row) * 128 + slot * 8);
        float4 f0 = src[0], f1 = src[1];
        uint4 v;
        v.x = cvt_pk_bf16(f0.x, f0.y);
        v.y = cvt_pk_bf16(f0.z, f0.w);
        v.z = cvt_pk_bf16(f1.x, f1.y);
        v.w = cvt_pk_bf16(f1.z, f1.w);
        *(uint4*)(sX + row * 256 + ((slot ^ (row & 15)) << 4)) = v;
    }
    // stage W^T: NF*16 cols x 128 k (bf16 direct copy, same swizzle)
    #pragma unroll
    for (int i = 0; i < NF; ++i) {
        const int c = t + 256 * i;
        const int col = c >> 4, slot = c & 15;
        uint4 v = *(const uint4*)(Wt + (size_t)(c0 + col) * 128 + slot * 8);
        *(uint4*)(sW + col * 256 + ((slot ^ (col & 15)) << 4)) = v;
    }
    __syncthreads();

    short8 aF[4];
    #pragma unroll
    for (int kk = 0; kk < 4; ++kk)
        aF[kk] = *(const short8*)(sX + (w * 16 + l15) * 256 + (((kk * 4 + l4) ^ l15) << 4));

    f32x4 acc[NF];
    #pragma unroll
    for (int nf = 0; nf < NF; ++nf) acc[nf] = f32x4{0.f, 0.f, 0.f, 0.f};
    #pragma unroll
    for (int nf = 0; nf < NF; ++nf) {
        #pragma unroll
        for (int kk = 0; kk < 4; ++kk) {
            short8 bF = *(const short8*)(sW + (nf * 16 + l15) * 256 + (((kk * 4 + l4) ^ l15) << 4));
            acc[nf] = __builtin_amdgcn_mfma_f32_16x16x32_bf16(bF, aF[kk], acc[nf], 0, 0, 0);
        }
    }

    const float scl = (MODE == 0 && blockIdx.y == 0) ? 0.25f : 1.0f;
    const int row = r0 + w * 16 + l15;                 // output row = X row (D col)
    #pragma unroll
    for (int nf = 0; nf < NF; ++nf) {
        const int cb = nf * 16 + l4 * 4;               // 4 consecutive output cols
        float4 bv = *(const float4*)(bias + c0 + cb);
        float v0 = acc[nf][0] + bv.x, v1 = acc[nf][1] + bv.y;
        float v2 = acc[nf][2] + bv.z, v3 = acc[nf][3] + bv.w;
        if (MODE == 1) {
            v0 = fmaxf(v0, 0.f); v1 = fmaxf(v1, 0.f);
            v2 = fmaxf(v2, 0.f); v3 = fmaxf(v3, 0.f);
        }
        v0 *= scl; v1 *= scl; v2 *= scl; v3 *= scl;
        uint2 pk;
        pk.x = cvt_pk_bf16(v0, v1);
        pk.y = cvt_pk_bf16(v2, v3);
        size_t o;
        if (MODE == 0) o = (size_t)blockIdx.y * ARRE + (size_t)row * 128 + cb;
        else           o = (size_t)row * 128 + c0 + cb;
        *(uint2*)(out + o) = pk;
    }
}

// ---------------------------------------------------------------- MFMA GEMM2 + residual + LN2 -> fp32 out
__global__ __launch_bounds__(256, 2) void k_mm2(const unsigned short* __restrict__ h1,
        const unsigned short* __restrict__ w2t, const float* __restrict__ b2,
        const float* __restrict__ x1, const float* __restrict__ g2,
        const float* __restrict__ be2, float* __restrict__ out)
{
    __shared__ char smem[16384 + 32768];
    char* const sX = smem;
    char* const sW = smem + 16384;
    const int t = threadIdx.x;
    const int w = t >> 6, l = t & 63;
    const int l4 = l >> 4, l15 = l & 15;
    const int r0 = blockIdx.x * 64;

    #pragma unroll
    for (int i = 0; i < 4; ++i) {
        const int c = t + 256 * i;
        const int row = c >> 4, slot = c & 15;
        uint4 v = *(const uint4*)(h1 + (size_t)(r0 + row) * 128 + slot * 8);
        *(uint4*)(sX + row * 256 + ((slot ^ (row & 15)) << 4)) = v;
    }
    #pragma unroll
    for (int i = 0; i < 8; ++i) {
        const int c = t + 256 * i;
        const int col = c >> 4, slot = c & 15;
        uint4 v = *(const uint4*)(w2t + (size_t)col * 128 + slot * 8);
        *(uint4*)(sW + col * 256 + ((slot ^ (col & 15)) << 4)) = v;
    }
    __syncthreads();

    short8 aF[4];
    #pragma unroll
    for (int kk = 0; kk < 4; ++kk)
        aF[kk] = *(const short8*)(sX + (w * 16 + l15) * 256 + (((kk * 4 + l4) ^ l15) << 4));

    f32x4 acc[8];
    #pragma unroll
    for (int nf = 0; nf < 8; ++nf) acc[nf] = f32x4{0.f, 0.f, 0.f, 0.f};
    #pragma unroll
    for (int nf = 0; nf < 8; ++nf) {
        #pragma unroll
        for (int kk = 0; kk < 4; ++kk) {
            short8 bF = *(const short8*)(sW + (nf * 16 + l15) * 256 + (((kk * 4 + l4) ^ l15) << 4));
            acc[nf] = __builtin_amdgcn_mfma_f32_16x16x32_bf16(bF, aF[kk], acc[nf], 0, 0, 0);
        }
    }

    // epilogue: y = acc + b2 + x1 ; row = r0 + w*16 + l15, cols nf*16 + l4*4 + reg
    const int row = r0 + w * 16 + l15;
    float y[8][4];
    float s = 0.f;
    #pragma unroll
    for (int nf = 0; nf < 8; ++nf) {
        const int cb = nf * 16 + l4 * 4;
        float4 bv = *(const float4*)(b2 + cb);
        float4 xv = *(const float4*)(x1 + (size_t)row * 128 + cb);
        y[nf][0] = acc[nf][0] + bv.x + xv.x;
        y[nf][1] = acc[nf][1] + bv.y + xv.y;
        y[nf][2] = acc[nf][2] + bv.z + xv.z;
        y[nf][3] = acc[nf][3] + bv.w + xv.w;
        s += y[nf][0] + y[nf][1] + y[nf][2] + y[nf][3];
    }
    // row sum: partner lanes are l^16, l^32 (same l15, different l4)
    s += __shfl_xor(s, 16); s += __shfl_xor(s, 32);
    const float mu = s * (1.f / 128.f);
    float vv = 0.f;
    #pragma unroll
    for (int nf = 0; nf < 8; ++nf) {
        #pragma unroll
        for (int reg = 0; reg < 4; ++reg) { float d = y[nf][reg] - mu; vv += d * d; }
    }
    vv += __shfl_xor(vv, 16); vv += __shfl_xor(vv, 32);
    const float rs = rsqrtf(vv * (1.f / 128.f) + 1e-5f);
    #pragma unroll
    for (int nf = 0; nf < 8; ++nf) {
        const int cb = nf * 16 + l4 * 4;
        float4 gv = *(const float4*)(g2 + cb);
        float4 ev = *(const float4*)(be2 + cb);
        float4 o;
        o.x = (y[nf][0] - mu) * rs * gv.x + ev.x;
        o.y = (y[nf][1] - mu) * rs * gv.y + ev.y;
        o.z = (y[nf][2] - mu) * rs * gv.z + ev.z;
        o.w = (y[nf][3] - mu) * rs * gv.w + ev.w;
        *(float4*)(out + (size_t)row * 128 + cb) = o;
    }
}

// ---------------------------------------------------------------- MFMA flash attention + fused LN1
// 512 threads = 8 waves, wave w owns head w; 32 q-rows per block.
__global__ __launch_bounds__(512, 2) void k_attn(
        const unsigned short* __restrict__ qb,
        const unsigned short* __restrict__ kb,
        const unsigned short* __restrict__ vbp,
        const void* __restrict__ maskp, const int* __restrict__ flag,
        const float* __restrict__ x, const float* __restrict__ g1,
        const float* __restrict__ be1, float* __restrict__ x1)
{
    __shared__ alignas(16) char smem[39072];
    char*          const sK = smem;
    char*          const sV = smem + 8192;
    char*          const sP = smem + 17440;
    unsigned char* const sM = (unsigned char*)(smem + 37920);
    float*         const sS = (float*)(smem + 38048);

    const int t  = threadIdx.x;
    const int w  = t >> 6;        // head
    const int l  = t & 63;
    const int b  = blockIdx.y;
    const int q0 = blockIdx.x * 32;
    const int q   = l & 31;
    const int hi  = l >> 5;
    const int l4  = l >> 4;
    const int l15 = l & 15;
    const int bytemask = *flag;

    short8 qf;
    {
        const size_t qrow = (size_t)(b * 1024 + q0 + q) * 128;
        qf = *(const short8*)(qb + qrow + w * 16 + hi * 8);
    }
    float m = -INFINITY, ls = 0.f;
    f32x4 ac0 = {0,0,0,0}, ac1 = {0,0,0,0};
    const f32x16 z16 = {};
    float* const sSw = sS + w * 32;
    char*  const Pw  = sP + w * 2560;

    const uint8_t* m8  = (const uint8_t*)maskp;
    const int*     m32 = (const int*)maskp;

    for (int kt = 0; kt < 32; ++kt) {
        const int k0 = kt * 32;
        __syncthreads();
        // ---- stage K (XOR-swizzled 16B slots) and V (per-head [32][18] short tiles) ----
        {
            const int row = t >> 4, slot = t & 15;
            const size_t src = (size_t)(b * 1024 + k0 + row) * 128 + slot * 8;
            uint4 kv = *(const uint4*)(kb + src);
            *(uint4*)(sK + row * 256 + ((slot ^ (row & 15)) << 4)) = kv;
            uint4 vv = *(const uint4*)(vbp + src);
            unsigned short* dh = (unsigned short*)(sV + (slot >> 1) * 1156);
            uint32_t* dst = (uint32_t*)(dh + row * 18 + (slot & 1) * 8);
            dst[0] = vv.x; dst[1] = vv.y; dst[2] = vv.z; dst[3] = vv.w;
        }
        // ---- stage mask keep-bits: [32 q] x 32 keys (4 bytes/q) ----
        if (t < 128) {
            const int mq = t >> 2, g = t & 3;
            const size_t moff = ((size_t)b << 20) + (size_t)(q0 + mq) * 1024
                              + (size_t)(k0 + g * 8);
            unsigned int bits = 0;
            if (bytemask) {
                uint64_t v = *(const uint64_t*)(m8 + moff);
                #pragma unroll
                for (int j = 0; j < 8; ++j)
                    bits |= ((((v >> (8 * j)) & 0xffull) == 0ull) ? 1u : 0u) << j;
            } else {
                const int4* p = (const int4*)(m32 + moff);
                int4 va = p[0], vc = p[1];
                bits = (va.x==0?1u:0u) | (va.y==0?2u:0u) | (va.z==0?4u:0u) | (va.w==0?8u:0u)
                     | (vc.x==0?16u:0u) | (vc.y==0?32u:0u) | (vc.z==0?64u:0u) | (vc.w==0?128u:0u);
            }
            sM[mq * 4 + g] = (unsigned char)bits;
        }
        __syncthreads();

        const uint32_t mk = *(const uint32_t*)(sM + q * 4);
        const uint32_t mks = mk >> (4 * hi);

        // ---- head step (head = w) ----
        short8 kf = *(const short8*)(sK + q * 256 + ((((w << 1) + hi) ^ (q & 15)) << 4));
        f32x16 sc = __builtin_amdgcn_mfma_f32_32x32x16_bf16(kf, qf, z16, 0, 0, 0);
        float sm = sc[0];
        #pragma unroll
        for (int r = 1; r < 16; ++r) sm = fmaxf(sm, sc[r]);
        sm = fmaxf(sm, __shfl_xor(sm, 32));
        if (__any(sm > m + 8.f)) {             // defer-max (THR=8)
            float nm = fmaxf(m, sm);
            float s  = __expf(m - nm);
            m = nm; ls *= s;
            sSw[q] = s;                        // lanes l and l^32 write same value
            float4 s0v = *(float4*)&sSw[l4 * 4];
            float4 s1v = *(float4*)&sSw[l4 * 4 + 16];
            ac0[0] *= s0v.x; ac0[1] *= s0v.y; ac0[2] *= s0v.z; ac0[3] *= s0v.w;
            ac1[0] *= s1v.x; ac1[1] *= s1v.y; ac1[2] *= s1v.z; ac1[3] *= s1v.w;
        }
        float p[16]; float lsum = 0.f;
        #pragma unroll
        for (int r = 0; r < 16; ++r) {
            const int c = (r & 3) + 8 * (r >> 2);       // key = c + 4*hi
            float pv = __expf(sc[r] - m);
            pv = ((mks >> c) & 1u) ? pv : 0.f;          // multiplicative mask
            lsum += pv; p[r] = pv;
        }
        ls += lsum;
        #pragma unroll
        for (int g = 0; g < 4; ++g) {
            uint2 pk;
            pk.x = cvt_pk_bf16(p[4*g+0], p[4*g+1]);
            pk.y = cvt_pk_bf16(p[4*g+2], p[4*g+3]);
            *(uint2*)(Pw + q * 80 + (8 * g + 4 * hi) * 2) = pk;
        }
        short8 pa0 = *(const short8*)(Pw + l15 * 80 + l4 * 16);
        short8 pa1 = *(const short8*)(Pw + (l15 + 16) * 80 + l4 * 16);
        const unsigned short* sVh = (const unsigned short*)(sV + w * 1156);
        short8 vf;
        #pragma unroll
        for (int j = 0; j < 8; ++j)
            vf[j] = (short)sVh[(l4 * 8 + j) * 18 + l15];
        ac0 = __builtin_amdgcn_mfma_f32_16x16x32_bf16(pa0, vf, ac0, 0, 0, 0);
        ac1 = __builtin_amdgcn_mfma_f32_16x16x32_bf16(pa1, vf, ac1, 0, 0, 0);
    }

    __syncthreads();
    // ---- epilogue: normalize, ctx -> LDS fp32 [32][132] ----
    float* const sC = (float*)smem;
    {
        float lt  = ls + __shfl_xor(ls, 32);
        float inv = 1.f / lt;
        sSw[q] = inv;
        float4 i0 = *(float4*)&sSw[l4 * 4];
        float4 i1 = *(float4*)&sSw[l4 * 4 + 16];
        const int cc = w * 16 + l15;
        sC[(l4 * 4 + 0) * 132 + cc]  = ac0[0] * i0.x;
        sC[(l4 * 4 + 1) * 132 + cc]  = ac0[1] * i0.y;
        sC[(l4 * 4 + 2) * 132 + cc]  = ac0[2] * i0.z;
        sC[(l4 * 4 + 3) * 132 + cc]  = ac0[3] * i0.w;
        sC[(l4 * 4 + 16) * 132 + cc] = ac1[0] * i1.x;
        sC[(l4 * 4 + 17) * 132 + cc] = ac1[1] * i1.y;
        sC[(l4 * 4 + 18) * 132 + cc] = ac1[2] * i1.z;
        sC[(l4 * 4 + 19) * 132 + cc] = ac1[3] * i1.w;
    }
    __syncthreads();

    // ---- fused LN1: x1 = LN(x + ctx); 16 lanes/row, 8 cols/lane ----
    {
        const int row = t >> 4;
        const int c0  = (t & 15) * 8;
        const size_t grow = (size_t)(b * 1024 + q0 + row);
        const float4* xp = (const float4*)(x + grow * 128 + c0);
        const float4* cp = (const float4*)(sC + row * 132 + c0);
        float y[8];
        float s = 0.f;
        #pragma unroll
        for (int j = 0; j < 2; ++j) {
            float4 xv = xp[j], cv = cp[j];
            y[4*j+0] = xv.x + cv.x; y[4*j+1] = xv.y + cv.y;
            y[4*j+2] = xv.z + cv.z; y[4*j+3] = xv.w + cv.w;
            s += y[4*j+0] + y[4*j+1] + y[4*j+2] + y[4*j+3];
        }
        s += __shfl_xor(s, 1); s += __shfl_xor(s, 2);
        s += __shfl_xor(s, 4); s += __shfl_xor(s, 8);
        const float mu = s * (1.f / 128.f);
        float vv = 0.f;
        #pragma unroll
        for (int e = 0; e < 8; ++e) { float d = y[e] - mu; vv += d * d; }
        vv += __shfl_xor(vv, 1); vv += __shfl_xor(vv, 2);
        vv += __shfl_xor(vv, 4); vv += __shfl_xor(vv, 8);
        const float rs = rsqrtf(vv * (1.f / 128.f) + 1e-5f);
        #pragma unroll
        for (int j = 0; j < 2; ++j) {
            float4 gv = *(const float4*)(g1 + c0 + 4 * j);
            float4 bv = *(const float4*)(be1 + c0 + 4 * j);
            float4 o;
            o.x = (y[4*j+0] - mu) * rs * gv.x + bv.x;
            o.y = (y[4*j+1] - mu) * rs * gv.y + bv.y;
            o.z = (y[4*j+2] - mu) * rs * gv.z + bv.z;
            o.w = (y[4*j+3] - mu) * rs * gv.w + bv.w;
            *(float4*)(x1 + grow * 128 + c0 + 4 * j) = o;
        }
    }
}

// ---------------------------------------------------------------- launch
extern "C" void kernel_launch(void* const* d_in, const int* in_sizes, int n_in,
                              void* d_out, int out_size, void* d_ws, size_t ws_size,
                              hipStream_t stream)
{
    const float* x    = (const float*)d_in[0];
    const void*  mask = d_in[1];
    const float* wqkv = (const float*)d_in[2];
    const float* bqkv = (const float*)d_in[3];
    const float* w1   = (const float*)d_in[4];
    const float* b1   = (const float*)d_in[5];
    const float* w2   = (const float*)d_in[6];
    const float* b2   = (const float*)d_in[7];
    const float* g1   = (const float*)d_in[8];
    const float* be1  = (const float*)d_in[9];
    const float* g2   = (const float*)d_in[10];
    const float* be2  = (const float*)d_in[11];
    float* out = (float*)d_out;

    char* base = (char*)d_ws;
    int* flag = (int*)base;
    unsigned short* qb  = (unsigned short*)(base + 256);                   // 4MB
    unsigned short* kb  = qb + ARRE;                                       // 4MB
    unsigned short* vb  = kb + ARRE;                                       // 4MB
    float* x1           = (float*)(base + 256 + (size_t)12 * 1024 * 1024); // 8MB
    unsigned short* wT  = (unsigned short*)(base + 256 + (size_t)20 * 1024 * 1024); // 160KB
    unsigned short* h1b = qb;   // overlays qb (dead after attn; stream-sequential)

    k_detect<<<1, 64, 0, stream>>>((const uint32_t*)mask, flag);
    k_castw<<<320, 256, 0, stream>>>(wqkv, w1, w2, wT);
    k_mm<8, 0><<<dim3(256, 3), 256, 0, stream>>>(x, wT, bqkv, qb);
    k_attn<<<dim3(32, 16), 512, 0, stream>>>(qb, kb, vb, mask, flag, x, g1, be1, x1);
    k_mm<4, 1><<<dim3(256, 2), 256, 0, stream>>>(x1, wT + 49152, b1, h1b);
    k_mm2<<<256, 256, 0, stream>>>(h1b, wT + 65536, b2, x1, g2, be2, out);
}